// Round 1
// baseline (342.700 us; speedup 1.0000x reference)
//
#include <hip/hip_runtime.h>
#include <math.h>

#define PI_F        3.14159265358979323846f
#define TWO_PI_F    6.2831853071795864769f
#define INV_TWO_PI_F 0.15915494309189533577f

// ------------------------------------------------------------------
// GEMM: y[r][c] = sum_k x[r][k] * W[c][k],  K=256, Do=64
// block = 256 threads, tile = 128 rows x 64 cols, thread = 8 rows x 4 cols
// ------------------------------------------------------------------
__global__ __launch_bounds__(256) void gemm_xwT_kernel(
    const float* __restrict__ x,
    const float* __restrict__ W,
    float* __restrict__ y)
{
    const int tid = threadIdx.x;
    const int tx  = tid & 15;          // col group: cols 4*tx .. 4*tx+3
    const int ty  = tid >> 4;          // row group: 8 rows
    const long rb = (long)blockIdx.x * 128 + (long)ty * 8;

    const float* xp = x + rb * 256;
    const int c0 = tx << 2;

    float acc[8][4];
    #pragma unroll
    for (int i = 0; i < 8; ++i)
        #pragma unroll
        for (int jj = 0; jj < 4; ++jj) acc[i][jj] = 0.0f;

    for (int k = 0; k < 256; k += 4) {
        float4 wv[4];
        #pragma unroll
        for (int jj = 0; jj < 4; ++jj)
            wv[jj] = *(const float4*)(W + (long)(c0 + jj) * 256 + k);
        #pragma unroll
        for (int i = 0; i < 8; ++i) {
            float4 xv = *(const float4*)(xp + (long)i * 256 + k);
            #pragma unroll
            for (int jj = 0; jj < 4; ++jj) {
                acc[i][jj] = fmaf(xv.x, wv[jj].x, acc[i][jj]);
                acc[i][jj] = fmaf(xv.y, wv[jj].y, acc[i][jj]);
                acc[i][jj] = fmaf(xv.z, wv[jj].z, acc[i][jj]);
                acc[i][jj] = fmaf(xv.w, wv[jj].w, acc[i][jj]);
            }
        }
    }

    #pragma unroll
    for (int i = 0; i < 8; ++i) {
        float4 o = make_float4(acc[i][0], acc[i][1], acc[i][2], acc[i][3]);
        *(float4*)(y + (rb + i) * 64 + c0) = o;
    }
}

// ------------------------------------------------------------------
// Projection: per group g (at level l), neighbors nh[g][0..7]:
//   logw[p][j] = -(dlat^2+dlon_w^2)/(2 sigma^2) + kappa*(cos(dlon_w)-1)
//   w = softmax_j(logw);  out[n=g*GS+p][d] = sum_j w[p][j]*y[nh[g][j]][d]
// One wave handles CG groups (CG*GS == ROUNDS*8 point-slots).
// Weight phase: lane = (pp<<3)|j; PV phase: lane = channel d.
// ------------------------------------------------------------------
template<int GS, int CG, int ROUNDS>
__global__ __launch_bounds__(256) void proj_kernel(
    const float* __restrict__ y,       // [B*N][64]
    const float* __restrict__ coords,  // [2][N]
    const int*   __restrict__ nh,      // [N][8]
    const float* __restrict__ oc,      // [2][B][N0]
    const float* __restrict__ sig_p,
    const float* __restrict__ kap_p,
    float* __restrict__ out,           // [B][N0][64]
    int N, int N0)
{
    constexpr int B = 2;
    static_assert(CG * GS == ROUNDS * 8, "slot layout");
    __shared__ float wlds[4][ROUNDS * 64];

    const int wslot = threadIdx.x >> 6;
    const int lane  = threadIdx.x & 63;
    const int wave  = (blockIdx.x << 2) + wslot;    // global wave id
    const int gpb   = N / CG;                       // group-chunks per batch
    const int b     = wave / gpb;
    const int g0    = (wave - b * gpb) * CG;

    const float sigma  = *sig_p;
    const float kappa  = *kap_p;
    const float inv2s2 = 1.0f / (2.0f * sigma * sigma);

    const int j  = lane & 7;
    const int pp = lane >> 3;

    #pragma unroll
    for (int r = 0; r < ROUNDS; ++r) {
        const int pidx = r * 8 + pp;
        const int q = pidx / GS;
        const int p = pidx - q * GS;
        const int g = g0 + q;
        const int idx = nh[g * 8 + j];
        const float clon = coords[idx];
        const float clat = coords[N + idx];
        const int n = g * GS + p;
        const float olon = oc[(long)b * N0 + n];
        const float olat = oc[(long)(B + b) * N0 + n];

        float dlon = olon - clon;
        float t = (dlon + PI_F) * INV_TWO_PI_F;   // floor-mod wrap to [-pi, pi)
        t -= floorf(t);
        dlon = t * TWO_PI_F - PI_F;
        const float dlat = olat - clat;

        float logw = -(dlat * dlat + dlon * dlon) * inv2s2
                   + kappa * (cosf(dlon) - 1.0f);

        // softmax over the 8 neighbor lanes
        float m = logw;
        m = fmaxf(m, __shfl_xor(m, 1));
        m = fmaxf(m, __shfl_xor(m, 2));
        m = fmaxf(m, __shfl_xor(m, 4));
        float e = expf(logw - m);
        float s = e;
        s += __shfl_xor(s, 1);
        s += __shfl_xor(s, 2);
        s += __shfl_xor(s, 4);
        wlds[wslot][r * 64 + lane] = e / s;
    }

    __syncthreads();

    const int d = lane;                 // channel
    const float* yb = y + (long)b * N * 64 + d;
    #pragma unroll
    for (int pidx = 0; pidx < CG * GS; ++pidx) {
        const int q = pidx / GS;
        const int p = pidx - q * GS;
        const int g = g0 + q;
        const int* nhg = nh + g * 8;
        const float* wrow = &wlds[wslot][pidx * 8];
        float a = 0.0f;
        #pragma unroll
        for (int jj = 0; jj < 8; ++jj)
            a = fmaf(wrow[jj], yb[(long)nhg[jj] * 64], a);
        const int n = g * GS + p;
        out[((long)b * N0 + n) * 64 + d] = a;
    }
}

// ------------------------------------------------------------------
extern "C" void kernel_launch(void* const* d_in, const int* in_sizes, int n_in,
                              void* d_out, int out_size, void* d_ws, size_t ws_size,
                              hipStream_t stream)
{
    const float* x0   = (const float*)d_in[0];
    const float* x1   = (const float*)d_in[1];
    const float* x2   = (const float*)d_in[2];
    const float* W0   = (const float*)d_in[3];
    const float* W1   = (const float*)d_in[4];
    const float* W2   = (const float*)d_in[5];
    const float* sig0 = (const float*)d_in[6];
    const float* sig1 = (const float*)d_in[7];
    const float* sig2 = (const float*)d_in[8];
    const float* kap0 = (const float*)d_in[9];
    const float* kap1 = (const float*)d_in[10];
    const float* kap2 = (const float*)d_in[11];
    const float* c0   = (const float*)d_in[12];
    const float* c1   = (const float*)d_in[13];
    const float* c2   = (const float*)d_in[14];
    const int*   nh0  = (const int*)d_in[15];
    const int*   nh1  = (const int*)d_in[16];
    const int*   nh2  = (const int*)d_in[17];
    const float* oc   = (const float*)d_in[18];

    float* out = (float*)d_out;
    const size_t SLICE = (size_t)2 * 65536 * 64;   // floats per output level slice
    // Stage y0/y1 in the out slice for level 2 (written before slice 2's final
    // contents are produced); y2 (2.1 MB) goes in d_ws.
    float* ystage = out + 2 * SLICE;
    float* y2     = (float*)d_ws;

    // ---- level 0: N=65536, GS=1, CG=8, ROUNDS=1
    gemm_xwT_kernel<<<131072 / 128, 256, 0, stream>>>(x0, W0, ystage);
    proj_kernel<1, 8, 1><<<(2 * 65536 / 8) / 4, 256, 0, stream>>>(
        ystage, c0, nh0, oc, sig0, kap0, out + 0 * SLICE, 65536, 65536);

    // ---- level 1: N=16384, GS=4, CG=2, ROUNDS=1
    gemm_xwT_kernel<<<32768 / 128, 256, 0, stream>>>(x1, W1, ystage);
    proj_kernel<4, 2, 1><<<(2 * 16384 / 2) / 4, 256, 0, stream>>>(
        ystage, c1, nh1, oc, sig1, kap1, out + 1 * SLICE, 16384, 65536);

    // ---- level 2: N=4096, GS=16, CG=1, ROUNDS=2
    gemm_xwT_kernel<<<8192 / 128, 256, 0, stream>>>(x2, W2, y2);
    proj_kernel<16, 1, 2><<<(2 * 4096 / 1) / 4, 256, 0, stream>>>(
        y2, c2, nh2, oc, sig2, kap2, out + 2 * SLICE, 4096, 65536);
}